// Round 7
// baseline (481.032 us; speedup 1.0000x reference)
//
#include <hip/hip_runtime.h>
#include <math.h>

#define L_SEQ 4096
#define C_DIM 512
#define NH 8
#define DK 64
#define NB 2
#define QSC 0.18033688011112042f  /* (1/sqrt(64)) * log2(e) */

typedef _Float16 f16;
typedef _Float16 f16x8 __attribute__((ext_vector_type(8)));
typedef _Float16 f16x4 __attribute__((ext_vector_type(4)));
typedef __fp16 h16x2 __attribute__((ext_vector_type(2)));   // builtin ABI type
typedef float f32x4 __attribute__((ext_vector_type(4)));

// ---------------------------------------------------------------------------
// prep: z=0,1 -> transpose-cast X[b] [512][4096] fp32 -> Xt [b*4096+t][512] f16
//       z=2   -> plain-cast Wq, Wkv[0:512], Wkv[512:1024], Wp -> f16
// ---------------------------------------------------------------------------
__global__ __launch_bounds__(256) void prep(
    const float* __restrict__ X, const float* __restrict__ Wq,
    const float* __restrict__ Wkv, const float* __restrict__ Wp,
    f16* __restrict__ Xt, f16* __restrict__ Wqkh,
    f16* __restrict__ Wvh, f16* __restrict__ Wph)
{
    const int tid = threadIdx.x;
    const int z = blockIdx.z;
    if (z < 2) {
        __shared__ f16 Ts[64][72];
        const float* src = X + (size_t)z * C_DIM * L_SEQ;
        f16* dst = Xt + (size_t)z * L_SEQ * C_DIM;
        for (int tile = blockIdx.x; tile < 512; tile += gridDim.x) {
            const int c0 = (tile & 7) * 64;
            const int t0 = (tile >> 3) * 64;
            __syncthreads();
            #pragma unroll
            for (int p = 0; p < 4; ++p) {
                const int c = (tid >> 4) + p * 16;
                const int t = (tid & 15) * 4;
                const float4 v = *(const float4*)(src + (size_t)(c0 + c) * L_SEQ + t0 + t);
                Ts[t + 0][c] = (f16)v.x; Ts[t + 1][c] = (f16)v.y;
                Ts[t + 2][c] = (f16)v.z; Ts[t + 3][c] = (f16)v.w;
            }
            __syncthreads();
            #pragma unroll
            for (int p = 0; p < 2; ++p) {
                const int t = (tid >> 3) + p * 32;
                const int ch = (tid & 7) * 8;
                *(f16x8*)(dst + (size_t)(t0 + t) * C_DIM + c0 + ch) =
                    *(const f16x8*)&Ts[t][ch];
            }
        }
    } else {
        const float* srcs[4] = {Wq, Wkv, Wkv + 262144, Wp};
        f16* dsts[4] = {Wqkh, Wqkh + 262144, Wvh, Wph};
        #pragma unroll
        for (int s = 0; s < 4; ++s) {
            const float* sp = srcs[s]; f16* dp = dsts[s];
            for (int i = blockIdx.x * 256 + tid; i < 65536; i += gridDim.x * 256) {
                const float4 v = *(const float4*)(sp + (size_t)i * 4);
                f16x4 h; h[0] = (f16)v.x; h[1] = (f16)v.y; h[2] = (f16)v.z; h[3] = (f16)v.w;
                *(f16x4*)(dp + (size_t)i * 4) = h;
            }
        }
    }
}

// ---------------------------------------------------------------------------
// Q/K projection, fp16 MFMA. m = tokens (global 8192), n = channels (1024).
// A = Xt[t][c], B = Wqkh[o][c]. C row=t, col=o. Q scaled by QSC.
// Outputs token-major Qh/Kh [bh][t][64].
// ---------------------------------------------------------------------------
__global__ __launch_bounds__(256) void qk_mfma(
    const f16* __restrict__ Xt, const f16* __restrict__ Wqkh,
    const float* __restrict__ bq, const float* __restrict__ bkv,
    f16* __restrict__ Qh, f16* __restrict__ Kh)
{
    __shared__ f16 As[128][40];
    __shared__ f16 Bs[128][40];
    const int tid = threadIdx.x;
    const int lane = tid & 63, w = tid >> 6;
    const int l15 = lane & 15, quad = lane >> 4;
    const int wy = w >> 1, wx = w & 1;
    const int mb0 = blockIdx.x * 128;   // token tile
    const int n0  = blockIdx.y * 128;   // channel tile

    f32x4 acc[4][4] = {};
    const int row = tid >> 2, c8 = (tid & 3) * 8;
    const f16* aptr = Xt + (size_t)mb0 * 512;
    const f16* bptr = Wqkh + (size_t)n0 * 512;

    uint4 ga0 = *(const uint4*)(aptr + (size_t)row * 512 + c8);
    uint4 ga1 = *(const uint4*)(aptr + (size_t)(row + 64) * 512 + c8);
    uint4 gb0 = *(const uint4*)(bptr + (size_t)row * 512 + c8);
    uint4 gb1 = *(const uint4*)(bptr + (size_t)(row + 64) * 512 + c8);

    for (int k0 = 0; k0 < 512; k0 += 32) {
        __syncthreads();
        *(uint4*)&As[row][c8] = ga0;
        *(uint4*)&As[row + 64][c8] = ga1;
        *(uint4*)&Bs[row][c8] = gb0;
        *(uint4*)&Bs[row + 64][c8] = gb1;
        if (k0 + 32 < 512) {
            ga0 = *(const uint4*)(aptr + (size_t)row * 512 + k0 + 32 + c8);
            ga1 = *(const uint4*)(aptr + (size_t)(row + 64) * 512 + k0 + 32 + c8);
            gb0 = *(const uint4*)(bptr + (size_t)row * 512 + k0 + 32 + c8);
            gb1 = *(const uint4*)(bptr + (size_t)(row + 64) * 512 + k0 + 32 + c8);
        }
        __syncthreads();
        f16x8 af[4], bf[4];
        #pragma unroll
        for (int i = 0; i < 4; ++i)
            af[i] = *(const f16x8*)&As[wy * 64 + i * 16 + l15][quad * 8];
        #pragma unroll
        for (int n = 0; n < 4; ++n)
            bf[n] = *(const f16x8*)&Bs[wx * 64 + n * 16 + l15][quad * 8];
        #pragma unroll
        for (int i = 0; i < 4; ++i)
            #pragma unroll
            for (int n = 0; n < 4; ++n)
                acc[i][n] = __builtin_amdgcn_mfma_f32_16x16x32_f16(af[i], bf[n], acc[i][n], 0, 0, 0);
    }

    #pragma unroll
    for (int nn = 0; nn < 4; ++nn) {
        const int o = n0 + wx * 64 + nn * 16 + l15;
        const bool isQ = (o < 512);
        const float bias = isQ ? bq[o] : bkv[o - 512];
        const int h = (o & 511) >> 6, d = o & 63;
        f16* base = isQ ? Qh : Kh;
        #pragma unroll
        for (int i = 0; i < 4; ++i) {
            const int tr = mb0 + wy * 64 + i * 16 + quad * 4;
            #pragma unroll
            for (int r = 0; r < 4; ++r) {
                const int tg = tr + r;
                const int bh = (tg >> 12) * NH + h;
                float v = acc[i][nn][r] + bias;
                if (isQ) v *= QSC;
                base[((size_t)bh * L_SEQ + (tg & 4095)) * DK + d] = (f16)v;
            }
        }
    }
}

// ---------------------------------------------------------------------------
// Channel-major projection, fp16 MFMA. m = channels (512), n = tokens (8192).
// A = Wh[o][c], B = Bsrc[t][c]. mode 0: V (f16 out, [bh*64+d][t]);
// mode 1: out-proj (fp32 out, [b][o][t]).
// ---------------------------------------------------------------------------
__global__ __launch_bounds__(256) void cproj_mfma(
    const f16* __restrict__ Bsrc, const f16* __restrict__ Wh,
    const float* __restrict__ bias, f16* __restrict__ outV,
    float* __restrict__ outP, int mode)
{
    __shared__ f16 As[128][40];
    __shared__ f16 Bs[128][40];
    const int tid = threadIdx.x;
    const int lane = tid & 63, w = tid >> 6;
    const int l15 = lane & 15, quad = lane >> 4;
    const int wy = w >> 1, wx = w & 1;
    const int n0  = blockIdx.x * 128;   // token tile
    const int mb0 = blockIdx.y * 128;   // channel tile

    f32x4 acc[4][4] = {};
    const int row = tid >> 2, c8 = (tid & 3) * 8;
    const f16* aptr = Wh + (size_t)mb0 * 512;
    const f16* bptr = Bsrc + (size_t)n0 * 512;

    uint4 ga0 = *(const uint4*)(aptr + (size_t)row * 512 + c8);
    uint4 ga1 = *(const uint4*)(aptr + (size_t)(row + 64) * 512 + c8);
    uint4 gb0 = *(const uint4*)(bptr + (size_t)row * 512 + c8);
    uint4 gb1 = *(const uint4*)(bptr + (size_t)(row + 64) * 512 + c8);

    for (int k0 = 0; k0 < 512; k0 += 32) {
        __syncthreads();
        *(uint4*)&As[row][c8] = ga0;
        *(uint4*)&As[row + 64][c8] = ga1;
        *(uint4*)&Bs[row][c8] = gb0;
        *(uint4*)&Bs[row + 64][c8] = gb1;
        if (k0 + 32 < 512) {
            ga0 = *(const uint4*)(aptr + (size_t)row * 512 + k0 + 32 + c8);
            ga1 = *(const uint4*)(aptr + (size_t)(row + 64) * 512 + k0 + 32 + c8);
            gb0 = *(const uint4*)(bptr + (size_t)row * 512 + k0 + 32 + c8);
            gb1 = *(const uint4*)(bptr + (size_t)(row + 64) * 512 + k0 + 32 + c8);
        }
        __syncthreads();
        f16x8 af[4], bf[4];
        #pragma unroll
        for (int i = 0; i < 4; ++i)
            af[i] = *(const f16x8*)&As[wy * 64 + i * 16 + l15][quad * 8];
        #pragma unroll
        for (int n = 0; n < 4; ++n)
            bf[n] = *(const f16x8*)&Bs[wx * 64 + n * 16 + l15][quad * 8];
        #pragma unroll
        for (int i = 0; i < 4; ++i)
            #pragma unroll
            for (int n = 0; n < 4; ++n)
                acc[i][n] = __builtin_amdgcn_mfma_f32_16x16x32_f16(af[i], bf[n], acc[i][n], 0, 0, 0);
    }

    #pragma unroll
    for (int i = 0; i < 4; ++i) {
        #pragma unroll
        for (int r = 0; r < 4; ++r) {
            const int o = mb0 + wy * 64 + i * 16 + quad * 4 + r;   // channel
            const float bv = bias[o];
            #pragma unroll
            for (int nn = 0; nn < 4; ++nn) {
                const int tg = n0 + wx * 64 + nn * 16 + l15;
                const float v = acc[i][nn][r] + bv;
                if (mode == 0) {
                    const int bh = (tg >> 12) * NH + (o >> 6);
                    outV[((size_t)bh * DK + (o & 63)) * L_SEQ + (tg & 4095)] = (f16)v;
                } else {
                    outP[((size_t)(tg >> 12) * C_DIM + o) * L_SEQ + (tg & 4095)] = v;
                }
            }
        }
    }
}

// ---------------------------------------------------------------------------
// Flash attention v6: split-s flash-decoding. blockIdx.z = s-half; each block
// does 2048 of the 4096 K/V positions -> grid 1024 = 4 blocks/CU. No-max
// softmax is additive, so partials (unnormalized O, l) combine trivially.
// Barrier-free; K register-prefetch; V issued early; raw v_exp_f32 +
// v_cvt_pkrtz + v_dot2 (l summed from the ROUNDED P, cancelling RTZ bias).
// Partial O stored f16 [half*16+bh][d][t]; l f32 [half*16+bh][t].
// ---------------------------------------------------------------------------
__global__ __launch_bounds__(256, 4) void flash16(
    const f16* __restrict__ Qh, const f16* __restrict__ Kh,
    const f16* __restrict__ Vh, f16* __restrict__ Opart,
    float* __restrict__ Lpart)
{
    __shared__ f16 PT[4][2][16][76];   // per-wave P^T [n][t][s]; pad 76
    const int tid = threadIdx.x;
    const int lane = tid & 63, w = tid >> 6;
    const int l15 = lane & 15, quad = lane >> 4;
    const int bh = blockIdx.x;          // XCD locality: bh % 8 picks the XCD
    const int t0 = blockIdx.y * 128;
    const int half = blockIdx.z;
    const int s_beg = half * 2048;
    const int wtb = t0 + w * 32;
    const f16* Qg = Qh + (size_t)bh * L_SEQ * DK;
    const f16* Kg = Kh + (size_t)bh * L_SEQ * DK;
    const f16* Vg = Vh + (size_t)bh * DK * L_SEQ;

    // persistent Q B-fragments (already scaled by QSC in qk_mfma)
    f16x8 qf[2][2];
    #pragma unroll
    for (int n = 0; n < 2; ++n)
        #pragma unroll
        for (int ks = 0; ks < 2; ++ks)
            qf[n][ks] = *(const f16x8*)(Qg + (size_t)(wtb + n * 16 + l15) * DK + ks * 32 + quad * 8);

    f32x4 o_acc[4][2] = {};
    float rs[2] = {0.f, 0.f};
    h16x2 one2; one2[0] = (__fp16)1.f; one2[1] = (__fp16)1.f;

    // K fragment base: row s = s0 + m*16 + l15, col d = ks*32 + quad*8
    const f16* kbase = Kg + (size_t)l15 * DK + quad * 8;
    const f16* vbase = Vg + (size_t)l15 * L_SEQ + quad * 8;

    f16x8 kc[4][2];
    #pragma unroll
    for (int m = 0; m < 4; ++m) {
        const f16* kr = kbase + (size_t)(s_beg + m * 16) * DK;
        kc[m][0] = *(const f16x8*)kr;
        kc[m][1] = *(const f16x8*)(kr + 32);
    }

    for (int s0 = s_beg; s0 < s_beg + 2048; s0 += 64) {
        // S^T = K·Q^T : row = s, col = t
        f32x4 S[4][2];
        #pragma unroll
        for (int m = 0; m < 4; ++m) {
            #pragma unroll
            for (int n = 0; n < 2; ++n) {
                f32x4 z = {0.f, 0.f, 0.f, 0.f};
                z = __builtin_amdgcn_mfma_f32_16x16x32_f16(kc[m][0], qf[n][0], z, 0, 0, 0);
                S[m][n] = __builtin_amdgcn_mfma_f32_16x16x32_f16(kc[m][1], qf[n][1], z, 0, 0, 0);
            }
        }

        // prefetch next iteration's K fragments (slack = rest of this iter)
        f16x8 kn[4][2];
        if (s0 + 64 < s_beg + 2048) {
            #pragma unroll
            for (int m = 0; m < 4; ++m) {
                const f16* kr = kbase + (size_t)(s0 + 64 + m * 16) * DK;
                kn[m][0] = *(const f16x8*)kr;
                kn[m][1] = *(const f16x8*)(kr + 32);
            }
        }
        // current V fragments, issued early (consumed after softmax)
        f16x8 vf[4][2];
        #pragma unroll
        for (int m = 0; m < 4; ++m) {
            const f16* vr = vbase + (size_t)(m * 16) * L_SEQ + s0;
            vf[m][0] = *(const f16x8*)vr;
            vf[m][1] = *(const f16x8*)(vr + 32);
        }

        // P = exp2(S') via raw v_exp_f32; pack RTZ; l += dot2(P_rounded, 1)
        #pragma unroll
        for (int n = 0; n < 2; ++n) {
            #pragma unroll
            for (int m = 0; m < 4; ++m) {
                const h16x2 q01 = __builtin_amdgcn_cvt_pkrtz(
                    __builtin_amdgcn_exp2f(S[m][n][0]),
                    __builtin_amdgcn_exp2f(S[m][n][1]));
                const h16x2 q23 = __builtin_amdgcn_cvt_pkrtz(
                    __builtin_amdgcn_exp2f(S[m][n][2]),
                    __builtin_amdgcn_exp2f(S[m][n][3]));
                rs[n] = __builtin_amdgcn_fdot2(q01, one2, rs[n], false);
                rs[n] = __builtin_amdgcn_fdot2(q23, one2, rs[n], false);
                union { h16x2 h2[2]; uint2 u2; } pr;
                pr.h2[0] = q01; pr.h2[1] = q23;
                *(uint2*)&PT[w][n][l15][m * 16 + quad * 4] = pr.u2;
            }
        }

        // O += P·V  (A = V-frag [d][s], B = P-frag from LDS)
        #pragma unroll
        for (int ks = 0; ks < 2; ++ks) {
            f16x8 pf[2];
            #pragma unroll
            for (int n = 0; n < 2; ++n)
                pf[n] = *(const f16x8*)&PT[w][n][l15][ks * 32 + quad * 8];
            #pragma unroll
            for (int m = 0; m < 4; ++m) {
                #pragma unroll
                for (int n = 0; n < 2; ++n)
                    o_acc[m][n] = __builtin_amdgcn_mfma_f32_16x16x32_f16(vf[m][ks], pf[n], o_acc[m][n], 0, 0, 0);
            }
        }

        #pragma unroll
        for (int m = 0; m < 4; ++m) {
            kc[m][0] = kn[m][0];
            kc[m][1] = kn[m][1];
        }
    }

    // l partial: reduce over quads, store from quad 0
    float r0 = rs[0], r1 = rs[1];
    r0 += __shfl_xor(r0, 16, 64); r0 += __shfl_xor(r0, 32, 64);
    r1 += __shfl_xor(r1, 16, 64); r1 += __shfl_xor(r1, 32, 64);
    if (quad == 0) {
        float* Lp = Lpart + (size_t)(half * 16 + bh) * L_SEQ + wtb;
        Lp[l15] = r0;
        Lp[16 + l15] = r1;
    }

    // O partial: C layout row = d = m*16+quad*4+r, col = t = wtb + n*16+l15
    f16* Op = Opart + (size_t)(half * 16 + bh) * DK * L_SEQ;
    #pragma unroll
    for (int m = 0; m < 4; ++m)
        #pragma unroll
        for (int n = 0; n < 2; ++n)
            #pragma unroll
            for (int r = 0; r < 4; ++r)
                Op[(size_t)(m * 16 + quad * 4 + r) * L_SEQ + wtb + n * 16 + l15] =
                    (f16)o_acc[m][n][r];
}

// ---------------------------------------------------------------------------
// combine: O = (Olo + Ohi) / (llo + lhi), transpose [d][t] -> token-major
// f16 [b*4096+t][512] for the out-proj B operand. One block per (bh, 64-t).
// ---------------------------------------------------------------------------
__global__ __launch_bounds__(256) void combine(
    const f16* __restrict__ Opart, const float* __restrict__ Lpart,
    f16* __restrict__ Oh)
{
    __shared__ f16 Ts[64][72];
    __shared__ float Linv[64];
    const int tid = threadIdx.x;
    const int bh = blockIdx.y, b = bh >> 3, h = bh & 7;
    const int t0 = blockIdx.x * 64;
    if (tid < 64) {
        const float lo = Lpart[(size_t)bh * L_SEQ + t0 + tid];
        const float hi = Lpart[(size_t)(16 + bh) * L_SEQ + t0 + tid];
        Linv[tid] = 1.f / (lo + hi);
    }
    __syncthreads();
    const f16* Plo = Opart + (size_t)bh * DK * L_SEQ;
    const f16* Phi = Opart + (size_t)(16 + bh) * DK * L_SEQ;
    const int d = tid >> 4;
    const int tt = (tid & 15) * 4;
    #pragma unroll
    for (int p = 0; p < 4; ++p) {
        const int dd = d + p * 16;
        const size_t off = (size_t)dd * L_SEQ + t0 + tt;
        const f16x4 lo = *(const f16x4*)(Plo + off);
        const f16x4 hi = *(const f16x4*)(Phi + off);
        #pragma unroll
        for (int j = 0; j < 4; ++j)
            Ts[tt + j][dd] = (f16)(((float)lo[j] + (float)hi[j]) * Linv[tt + j]);
    }
    __syncthreads();
    const int tr = tid >> 2, ch = (tid & 3) * 16;
    f16* dst = Oh + ((size_t)(b * L_SEQ + t0 + tr)) * C_DIM + h * DK + ch;
    *(f16x8*)dst = *(const f16x8*)&Ts[tr][ch];
    *(f16x8*)(dst + 8) = *(const f16x8*)&Ts[tr][ch + 8];
}

// ---------------------------------------------------------------------------
extern "C" void kernel_launch(void* const* d_in, const int* in_sizes, int n_in,
                              void* d_out, int out_size, void* d_ws, size_t ws_size,
                              hipStream_t stream) {
    (void)in_sizes; (void)n_in; (void)out_size; (void)ws_size;
    const float* x   = (const float*)d_in[0];
    const float* Wq  = (const float*)d_in[1];
    const float* bq  = (const float*)d_in[2];
    const float* Wkv = (const float*)d_in[3];
    const float* bkv = (const float*)d_in[4];
    const float* Wp  = (const float*)d_in[5];
    const float* bp  = (const float*)d_in[6];
    float* out = (float*)d_out;

    f16* Xt    = (f16*)d_ws;           // [8192][512]
    f16* Wqkh  = Xt + 4194304;         // [1024][512]
    f16* Wvh   = Wqkh + 524288;        // [512][512]
    f16* Wph   = Wvh + 262144;         // [512][512]
    f16* Qh    = Wph + 262144;         // [16][4096][64]
    f16* Kh    = Qh + 4194304;
    f16* Vh    = Kh + 4194304;         // [16*64][4096]
    f16* Oh    = Vh + 4194304;         // [8192][512]
    f16* Opart = Oh + 4194304;         // [2*16][64][4096] f16
    float* Lpart = (float*)(Opart + 8388608);  // [2*16][4096] f32

    prep<<<dim3(128, 1, 3), 256, 0, stream>>>(x, Wq, Wkv, Wp, Xt, Wqkh, Wvh, Wph);
    qk_mfma<<<dim3(64, 8), 256, 0, stream>>>(Xt, Wqkh, bq, bkv, Qh, Kh);
    cproj_mfma<<<dim3(64, 4), 256, 0, stream>>>(Xt, Wvh, bkv + 512, Vh, nullptr, 0);
    flash16<<<dim3(16, 32, 2), 256, 0, stream>>>(Qh, Kh, Vh, Opart, Lpart);
    combine<<<dim3(64, 16), 256, 0, stream>>>(Opart, Lpart, Oh);
    cproj_mfma<<<dim3(64, 4), 256, 0, stream>>>(Oh, Wph, bp, nullptr, out, 1);
}

// Round 8
// 360.936 us; speedup vs baseline: 1.3327x; 1.3327x over previous
//
#include <hip/hip_runtime.h>
#include <math.h>

#define L_SEQ 4096
#define C_DIM 512
#define NH 8
#define DK 64
#define NB 2
#define QSC 0.18033688011112042f  /* (1/sqrt(64)) * log2(e) */

typedef _Float16 f16;
typedef _Float16 f16x8 __attribute__((ext_vector_type(8)));
typedef _Float16 f16x4 __attribute__((ext_vector_type(4)));
typedef __fp16 h16x2 __attribute__((ext_vector_type(2)));   // builtin ABI type
typedef float f32x4 __attribute__((ext_vector_type(4)));

// ---------------------------------------------------------------------------
// prep: z=0,1 -> transpose-cast X[b] [512][4096] fp32 -> Xt [b*4096+t][512] f16
//       z=2   -> plain-cast Wq, Wkv[0:512], Wkv[512:1024], Wp -> f16
// ---------------------------------------------------------------------------
__global__ __launch_bounds__(256) void prep(
    const float* __restrict__ X, const float* __restrict__ Wq,
    const float* __restrict__ Wkv, const float* __restrict__ Wp,
    f16* __restrict__ Xt, f16* __restrict__ Wqkh,
    f16* __restrict__ Wvh, f16* __restrict__ Wph)
{
    const int tid = threadIdx.x;
    const int z = blockIdx.z;
    if (z < 2) {
        __shared__ f16 Ts[64][72];
        const float* src = X + (size_t)z * C_DIM * L_SEQ;
        f16* dst = Xt + (size_t)z * L_SEQ * C_DIM;
        for (int tile = blockIdx.x; tile < 512; tile += gridDim.x) {
            const int c0 = (tile & 7) * 64;
            const int t0 = (tile >> 3) * 64;
            __syncthreads();
            #pragma unroll
            for (int p = 0; p < 4; ++p) {
                const int c = (tid >> 4) + p * 16;
                const int t = (tid & 15) * 4;
                const float4 v = *(const float4*)(src + (size_t)(c0 + c) * L_SEQ + t0 + t);
                Ts[t + 0][c] = (f16)v.x; Ts[t + 1][c] = (f16)v.y;
                Ts[t + 2][c] = (f16)v.z; Ts[t + 3][c] = (f16)v.w;
            }
            __syncthreads();
            #pragma unroll
            for (int p = 0; p < 2; ++p) {
                const int t = (tid >> 3) + p * 32;
                const int ch = (tid & 7) * 8;
                *(f16x8*)(dst + (size_t)(t0 + t) * C_DIM + c0 + ch) =
                    *(const f16x8*)&Ts[t][ch];
            }
        }
    } else {
        const float* srcs[4] = {Wq, Wkv, Wkv + 262144, Wp};
        f16* dsts[4] = {Wqkh, Wqkh + 262144, Wvh, Wph};
        #pragma unroll
        for (int s = 0; s < 4; ++s) {
            const float* sp = srcs[s]; f16* dp = dsts[s];
            for (int i = blockIdx.x * 256 + tid; i < 65536; i += gridDim.x * 256) {
                const float4 v = *(const float4*)(sp + (size_t)i * 4);
                f16x4 h; h[0] = (f16)v.x; h[1] = (f16)v.y; h[2] = (f16)v.z; h[3] = (f16)v.w;
                *(f16x4*)(dp + (size_t)i * 4) = h;
            }
        }
    }
}

// ---------------------------------------------------------------------------
// Q/K projection, fp16 MFMA. m = tokens (global 8192), n = channels (1024).
// A = Xt[t][c], B = Wqkh[o][c]. C row=t, col=o. Q scaled by QSC.
// Outputs token-major Qh/Kh [bh][t][64].
// ---------------------------------------------------------------------------
__global__ __launch_bounds__(256) void qk_mfma(
    const f16* __restrict__ Xt, const f16* __restrict__ Wqkh,
    const float* __restrict__ bq, const float* __restrict__ bkv,
    f16* __restrict__ Qh, f16* __restrict__ Kh)
{
    __shared__ f16 As[128][40];
    __shared__ f16 Bs[128][40];
    const int tid = threadIdx.x;
    const int lane = tid & 63, w = tid >> 6;
    const int l15 = lane & 15, quad = lane >> 4;
    const int wy = w >> 1, wx = w & 1;
    const int mb0 = blockIdx.x * 128;   // token tile
    const int n0  = blockIdx.y * 128;   // channel tile

    f32x4 acc[4][4] = {};
    const int row = tid >> 2, c8 = (tid & 3) * 8;
    const f16* aptr = Xt + (size_t)mb0 * 512;
    const f16* bptr = Wqkh + (size_t)n0 * 512;

    uint4 ga0 = *(const uint4*)(aptr + (size_t)row * 512 + c8);
    uint4 ga1 = *(const uint4*)(aptr + (size_t)(row + 64) * 512 + c8);
    uint4 gb0 = *(const uint4*)(bptr + (size_t)row * 512 + c8);
    uint4 gb1 = *(const uint4*)(bptr + (size_t)(row + 64) * 512 + c8);

    for (int k0 = 0; k0 < 512; k0 += 32) {
        __syncthreads();
        *(uint4*)&As[row][c8] = ga0;
        *(uint4*)&As[row + 64][c8] = ga1;
        *(uint4*)&Bs[row][c8] = gb0;
        *(uint4*)&Bs[row + 64][c8] = gb1;
        if (k0 + 32 < 512) {
            ga0 = *(const uint4*)(aptr + (size_t)row * 512 + k0 + 32 + c8);
            ga1 = *(const uint4*)(aptr + (size_t)(row + 64) * 512 + k0 + 32 + c8);
            gb0 = *(const uint4*)(bptr + (size_t)row * 512 + k0 + 32 + c8);
            gb1 = *(const uint4*)(bptr + (size_t)(row + 64) * 512 + k0 + 32 + c8);
        }
        __syncthreads();
        f16x8 af[4], bf[4];
        #pragma unroll
        for (int i = 0; i < 4; ++i)
            af[i] = *(const f16x8*)&As[wy * 64 + i * 16 + l15][quad * 8];
        #pragma unroll
        for (int n = 0; n < 4; ++n)
            bf[n] = *(const f16x8*)&Bs[wx * 64 + n * 16 + l15][quad * 8];
        #pragma unroll
        for (int i = 0; i < 4; ++i)
            #pragma unroll
            for (int n = 0; n < 4; ++n)
                acc[i][n] = __builtin_amdgcn_mfma_f32_16x16x32_f16(af[i], bf[n], acc[i][n], 0, 0, 0);
    }

    #pragma unroll
    for (int nn = 0; nn < 4; ++nn) {
        const int o = n0 + wx * 64 + nn * 16 + l15;
        const bool isQ = (o < 512);
        const float bias = isQ ? bq[o] : bkv[o - 512];
        const int h = (o & 511) >> 6, d = o & 63;
        f16* base = isQ ? Qh : Kh;
        #pragma unroll
        for (int i = 0; i < 4; ++i) {
            const int tr = mb0 + wy * 64 + i * 16 + quad * 4;
            #pragma unroll
            for (int r = 0; r < 4; ++r) {
                const int tg = tr + r;
                const int bh = (tg >> 12) * NH + h;
                float v = acc[i][nn][r] + bias;
                if (isQ) v *= QSC;
                base[((size_t)bh * L_SEQ + (tg & 4095)) * DK + d] = (f16)v;
            }
        }
    }
}

// ---------------------------------------------------------------------------
// Channel-major projection, fp16 MFMA. m = channels (512), n = tokens (8192).
// A = Wh[o][c], B = Bsrc[t][c]. mode 0: V (f16 out, [bh*64+d][t]);
// mode 1: out-proj (fp32 out, [b][o][t]).
// ---------------------------------------------------------------------------
__global__ __launch_bounds__(256) void cproj_mfma(
    const f16* __restrict__ Bsrc, const f16* __restrict__ Wh,
    const float* __restrict__ bias, f16* __restrict__ outV,
    float* __restrict__ outP, int mode)
{
    __shared__ f16 As[128][40];
    __shared__ f16 Bs[128][40];
    const int tid = threadIdx.x;
    const int lane = tid & 63, w = tid >> 6;
    const int l15 = lane & 15, quad = lane >> 4;
    const int wy = w >> 1, wx = w & 1;
    const int n0  = blockIdx.x * 128;   // token tile
    const int mb0 = blockIdx.y * 128;   // channel tile

    f32x4 acc[4][4] = {};
    const int row = tid >> 2, c8 = (tid & 3) * 8;
    const f16* aptr = Wh + (size_t)mb0 * 512;
    const f16* bptr = Bsrc + (size_t)n0 * 512;

    uint4 ga0 = *(const uint4*)(aptr + (size_t)row * 512 + c8);
    uint4 ga1 = *(const uint4*)(aptr + (size_t)(row + 64) * 512 + c8);
    uint4 gb0 = *(const uint4*)(bptr + (size_t)row * 512 + c8);
    uint4 gb1 = *(const uint4*)(bptr + (size_t)(row + 64) * 512 + c8);

    for (int k0 = 0; k0 < 512; k0 += 32) {
        __syncthreads();
        *(uint4*)&As[row][c8] = ga0;
        *(uint4*)&As[row + 64][c8] = ga1;
        *(uint4*)&Bs[row][c8] = gb0;
        *(uint4*)&Bs[row + 64][c8] = gb1;
        if (k0 + 32 < 512) {
            ga0 = *(const uint4*)(aptr + (size_t)row * 512 + k0 + 32 + c8);
            ga1 = *(const uint4*)(aptr + (size_t)(row + 64) * 512 + k0 + 32 + c8);
            gb0 = *(const uint4*)(bptr + (size_t)row * 512 + k0 + 32 + c8);
            gb1 = *(const uint4*)(bptr + (size_t)(row + 64) * 512 + k0 + 32 + c8);
        }
        __syncthreads();
        f16x8 af[4], bf[4];
        #pragma unroll
        for (int i = 0; i < 4; ++i)
            af[i] = *(const f16x8*)&As[wy * 64 + i * 16 + l15][quad * 8];
        #pragma unroll
        for (int n = 0; n < 4; ++n)
            bf[n] = *(const f16x8*)&Bs[wx * 64 + n * 16 + l15][quad * 8];
        #pragma unroll
        for (int i = 0; i < 4; ++i)
            #pragma unroll
            for (int n = 0; n < 4; ++n)
                acc[i][n] = __builtin_amdgcn_mfma_f32_16x16x32_f16(af[i], bf[n], acc[i][n], 0, 0, 0);
    }

    #pragma unroll
    for (int i = 0; i < 4; ++i) {
        #pragma unroll
        for (int r = 0; r < 4; ++r) {
            const int o = mb0 + wy * 64 + i * 16 + quad * 4 + r;   // channel
            const float bv = bias[o];
            #pragma unroll
            for (int nn = 0; nn < 4; ++nn) {
                const int tg = n0 + wx * 64 + nn * 16 + l15;
                const float v = acc[i][nn][r] + bv;
                if (mode == 0) {
                    const int bh = (tg >> 12) * NH + (o >> 6);
                    outV[((size_t)bh * DK + (o & 63)) * L_SEQ + (tg & 4095)] = (f16)v;
                } else {
                    outP[((size_t)(tg >> 12) * C_DIM + o) * L_SEQ + (tg & 4095)] = v;
                }
            }
        }
    }
}

// ---------------------------------------------------------------------------
// Flash attention v7: split-s flash-decoding, NO register cap (R7's
// __launch_bounds__(256,4) forced VGPR=64 -> 773 MB of scratch spill).
// Compiler allocates ~100-110 VGPR -> 4 waves/SIMD naturally; grid 1024
// = 4 blocks/CU. Barrier-free, no-max softmax, K register-prefetch,
// V issued early, raw v_exp_f32 + v_cvt_pkrtz + v_dot2.
// Partial O stored f16 [half*16+bh][d][t]; l f32 [half*16+bh][t].
// ---------------------------------------------------------------------------
__global__ __launch_bounds__(256) void flash16(
    const f16* __restrict__ Qh, const f16* __restrict__ Kh,
    const f16* __restrict__ Vh, f16* __restrict__ Opart,
    float* __restrict__ Lpart)
{
    __shared__ f16 PT[4][2][16][76];   // per-wave P^T [n][t][s]; pad 76
    const int tid = threadIdx.x;
    const int lane = tid & 63, w = tid >> 6;
    const int l15 = lane & 15, quad = lane >> 4;
    const int bh = blockIdx.x;          // XCD locality: bh % 8 picks the XCD
    const int t0 = blockIdx.y * 128;
    const int half = blockIdx.z;
    const int s_beg = half * 2048;
    const int wtb = t0 + w * 32;
    const f16* Qg = Qh + (size_t)bh * L_SEQ * DK;
    const f16* Kg = Kh + (size_t)bh * L_SEQ * DK;
    const f16* Vg = Vh + (size_t)bh * DK * L_SEQ;

    // persistent Q B-fragments (already scaled by QSC in qk_mfma)
    f16x8 qf[2][2];
    #pragma unroll
    for (int n = 0; n < 2; ++n)
        #pragma unroll
        for (int ks = 0; ks < 2; ++ks)
            qf[n][ks] = *(const f16x8*)(Qg + (size_t)(wtb + n * 16 + l15) * DK + ks * 32 + quad * 8);

    f32x4 o_acc[4][2] = {};
    float rs[2] = {0.f, 0.f};
    h16x2 one2; one2[0] = (__fp16)1.f; one2[1] = (__fp16)1.f;

    // K fragment base: row s = s0 + m*16 + l15, col d = ks*32 + quad*8
    const f16* kbase = Kg + (size_t)l15 * DK + quad * 8;
    const f16* vbase = Vg + (size_t)l15 * L_SEQ + quad * 8;

    f16x8 kc[4][2];
    #pragma unroll
    for (int m = 0; m < 4; ++m) {
        const f16* kr = kbase + (size_t)(s_beg + m * 16) * DK;
        kc[m][0] = *(const f16x8*)kr;
        kc[m][1] = *(const f16x8*)(kr + 32);
    }

    for (int s0 = s_beg; s0 < s_beg + 2048; s0 += 64) {
        // S^T = K·Q^T : row = s, col = t
        f32x4 S[4][2];
        #pragma unroll
        for (int m = 0; m < 4; ++m) {
            #pragma unroll
            for (int n = 0; n < 2; ++n) {
                f32x4 z = {0.f, 0.f, 0.f, 0.f};
                z = __builtin_amdgcn_mfma_f32_16x16x32_f16(kc[m][0], qf[n][0], z, 0, 0, 0);
                S[m][n] = __builtin_amdgcn_mfma_f32_16x16x32_f16(kc[m][1], qf[n][1], z, 0, 0, 0);
            }
        }

        // prefetch next iteration's K fragments (slack = rest of this iter)
        f16x8 kn[4][2];
        if (s0 + 64 < s_beg + 2048) {
            #pragma unroll
            for (int m = 0; m < 4; ++m) {
                const f16* kr = kbase + (size_t)(s0 + 64 + m * 16) * DK;
                kn[m][0] = *(const f16x8*)kr;
                kn[m][1] = *(const f16x8*)(kr + 32);
            }
        }
        // current V fragments, issued early (consumed after softmax)
        f16x8 vf[4][2];
        #pragma unroll
        for (int m = 0; m < 4; ++m) {
            const f16* vr = vbase + (size_t)(m * 16) * L_SEQ + s0;
            vf[m][0] = *(const f16x8*)vr;
            vf[m][1] = *(const f16x8*)(vr + 32);
        }

        // P = exp2(S') via raw v_exp_f32; pack RTZ; l += dot2(P_rounded, 1)
        #pragma unroll
        for (int n = 0; n < 2; ++n) {
            #pragma unroll
            for (int m = 0; m < 4; ++m) {
                const h16x2 q01 = __builtin_amdgcn_cvt_pkrtz(
                    __builtin_amdgcn_exp2f(S[m][n][0]),
                    __builtin_amdgcn_exp2f(S[m][n][1]));
                const h16x2 q23 = __builtin_amdgcn_cvt_pkrtz(
                    __builtin_amdgcn_exp2f(S[m][n][2]),
                    __builtin_amdgcn_exp2f(S[m][n][3]));
                rs[n] = __builtin_amdgcn_fdot2(q01, one2, rs[n], false);
                rs[n] = __builtin_amdgcn_fdot2(q23, one2, rs[n], false);
                union { h16x2 h2[2]; uint2 u2; } pr;
                pr.h2[0] = q01; pr.h2[1] = q23;
                *(uint2*)&PT[w][n][l15][m * 16 + quad * 4] = pr.u2;
            }
        }

        // O += P·V  (A = V-frag [d][s], B = P-frag from LDS)
        #pragma unroll
        for (int ks = 0; ks < 2; ++ks) {
            f16x8 pf[2];
            #pragma unroll
            for (int n = 0; n < 2; ++n)
                pf[n] = *(const f16x8*)&PT[w][n][l15][ks * 32 + quad * 8];
            #pragma unroll
            for (int m = 0; m < 4; ++m) {
                #pragma unroll
                for (int n = 0; n < 2; ++n)
                    o_acc[m][n] = __builtin_amdgcn_mfma_f32_16x16x32_f16(vf[m][ks], pf[n], o_acc[m][n], 0, 0, 0);
            }
        }

        #pragma unroll
        for (int m = 0; m < 4; ++m) {
            kc[m][0] = kn[m][0];
            kc[m][1] = kn[m][1];
        }
    }

    // l partial: reduce over quads, store from quad 0
    float r0 = rs[0], r1 = rs[1];
    r0 += __shfl_xor(r0, 16, 64); r0 += __shfl_xor(r0, 32, 64);
    r1 += __shfl_xor(r1, 16, 64); r1 += __shfl_xor(r1, 32, 64);
    if (quad == 0) {
        float* Lp = Lpart + (size_t)(half * 16 + bh) * L_SEQ + wtb;
        Lp[l15] = r0;
        Lp[16 + l15] = r1;
    }

    // O partial: C layout row = d = m*16+quad*4+r, col = t = wtb + n*16+l15
    f16* Op = Opart + (size_t)(half * 16 + bh) * DK * L_SEQ;
    #pragma unroll
    for (int m = 0; m < 4; ++m)
        #pragma unroll
        for (int n = 0; n < 2; ++n)
            #pragma unroll
            for (int r = 0; r < 4; ++r)
                Op[(size_t)(m * 16 + quad * 4 + r) * L_SEQ + wtb + n * 16 + l15] =
                    (f16)o_acc[m][n][r];
}

// ---------------------------------------------------------------------------
// combine: O = (Olo + Ohi) / (llo + lhi), transpose [d][t] -> token-major
// f16 [b*4096+t][512] for the out-proj B operand. One block per (bh, 64-t).
// ---------------------------------------------------------------------------
__global__ __launch_bounds__(256) void combine(
    const f16* __restrict__ Opart, const float* __restrict__ Lpart,
    f16* __restrict__ Oh)
{
    __shared__ f16 Ts[64][72];
    __shared__ float Linv[64];
    const int tid = threadIdx.x;
    const int bh = blockIdx.y, b = bh >> 3, h = bh & 7;
    const int t0 = blockIdx.x * 64;
    if (tid < 64) {
        const float lo = Lpart[(size_t)bh * L_SEQ + t0 + tid];
        const float hi = Lpart[(size_t)(16 + bh) * L_SEQ + t0 + tid];
        Linv[tid] = 1.f / (lo + hi);
    }
    __syncthreads();
    const f16* Plo = Opart + (size_t)bh * DK * L_SEQ;
    const f16* Phi = Opart + (size_t)(16 + bh) * DK * L_SEQ;
    const int d = tid >> 4;
    const int tt = (tid & 15) * 4;
    #pragma unroll
    for (int p = 0; p < 4; ++p) {
        const int dd = d + p * 16;
        const size_t off = (size_t)dd * L_SEQ + t0 + tt;
        const f16x4 lo = *(const f16x4*)(Plo + off);
        const f16x4 hi = *(const f16x4*)(Phi + off);
        #pragma unroll
        for (int j = 0; j < 4; ++j)
            Ts[tt + j][dd] = (f16)(((float)lo[j] + (float)hi[j]) * Linv[tt + j]);
    }
    __syncthreads();
    const int tr = tid >> 2, ch = (tid & 3) * 16;
    f16* dst = Oh + ((size_t)(b * L_SEQ + t0 + tr)) * C_DIM + h * DK + ch;
    *(f16x8*)dst = *(const f16x8*)&Ts[tr][ch];
    *(f16x8*)(dst + 8) = *(const f16x8*)&Ts[tr][ch + 8];
}

// ---------------------------------------------------------------------------
extern "C" void kernel_launch(void* const* d_in, const int* in_sizes, int n_in,
                              void* d_out, int out_size, void* d_ws, size_t ws_size,
                              hipStream_t stream) {
    (void)in_sizes; (void)n_in; (void)out_size; (void)ws_size;
    const float* x   = (const float*)d_in[0];
    const float* Wq  = (const float*)d_in[1];
    const float* bq  = (const float*)d_in[2];
    const float* Wkv = (const float*)d_in[3];
    const float* bkv = (const float*)d_in[4];
    const float* Wp  = (const float*)d_in[5];
    const float* bp  = (const float*)d_in[6];
    float* out = (float*)d_out;

    f16* Xt    = (f16*)d_ws;           // [8192][512]
    f16* Wqkh  = Xt + 4194304;         // [1024][512]
    f16* Wvh   = Wqkh + 524288;        // [512][512]
    f16* Wph   = Wvh + 262144;         // [512][512]
    f16* Qh    = Wph + 262144;         // [16][4096][64]
    f16* Kh    = Qh + 4194304;
    f16* Vh    = Kh + 4194304;         // [16*64][4096]
    f16* Oh    = Vh + 4194304;         // [8192][512]
    f16* Opart = Oh + 4194304;         // [2*16][64][4096] f16
    float* Lpart = (float*)(Opart + 8388608);  // [2*16][4096] f32

    prep<<<dim3(128, 1, 3), 256, 0, stream>>>(x, Wq, Wkv, Wp, Xt, Wqkh, Wvh, Wph);
    qk_mfma<<<dim3(64, 8), 256, 0, stream>>>(Xt, Wqkh, bq, bkv, Qh, Kh);
    cproj_mfma<<<dim3(64, 4), 256, 0, stream>>>(Xt, Wvh, bkv + 512, Vh, nullptr, 0);
    flash16<<<dim3(16, 32, 2), 256, 0, stream>>>(Qh, Kh, Vh, Opart, Lpart);
    combine<<<dim3(64, 16), 256, 0, stream>>>(Opart, Lpart, Oh);
    cproj_mfma<<<dim3(64, 4), 256, 0, stream>>>(Oh, Wph, bp, nullptr, out, 1);
}

// Round 9
// 283.640 us; speedup vs baseline: 1.6959x; 1.2725x over previous
//
#include <hip/hip_runtime.h>
#include <math.h>

#define L_SEQ 4096
#define C_DIM 512
#define NH 8
#define DK 64
#define NB 2
#define QSC 0.18033688011112042f  /* (1/sqrt(64)) * log2(e) */

typedef _Float16 f16;
typedef _Float16 f16x8 __attribute__((ext_vector_type(8)));
typedef _Float16 f16x4 __attribute__((ext_vector_type(4)));
typedef __fp16 h16x2 __attribute__((ext_vector_type(2)));   // builtin ABI type
typedef float f32x4 __attribute__((ext_vector_type(4)));

// ---------------------------------------------------------------------------
// prep: z=0,1 -> transpose-cast X[b] [512][4096] fp32 -> Xt [b*4096+t][512] f16
//       z=2   -> plain-cast Wq, Wkv[0:512], Wkv[512:1024], Wp -> f16
// ---------------------------------------------------------------------------
__global__ __launch_bounds__(256) void prep(
    const float* __restrict__ X, const float* __restrict__ Wq,
    const float* __restrict__ Wkv, const float* __restrict__ Wp,
    f16* __restrict__ Xt, f16* __restrict__ Wqkh,
    f16* __restrict__ Wvh, f16* __restrict__ Wph)
{
    const int tid = threadIdx.x;
    const int z = blockIdx.z;
    if (z < 2) {
        __shared__ f16 Ts[64][72];
        const float* src = X + (size_t)z * C_DIM * L_SEQ;
        f16* dst = Xt + (size_t)z * L_SEQ * C_DIM;
        for (int tile = blockIdx.x; tile < 512; tile += gridDim.x) {
            const int c0 = (tile & 7) * 64;
            const int t0 = (tile >> 3) * 64;
            __syncthreads();
            #pragma unroll
            for (int p = 0; p < 4; ++p) {
                const int c = (tid >> 4) + p * 16;
                const int t = (tid & 15) * 4;
                const float4 v = *(const float4*)(src + (size_t)(c0 + c) * L_SEQ + t0 + t);
                Ts[t + 0][c] = (f16)v.x; Ts[t + 1][c] = (f16)v.y;
                Ts[t + 2][c] = (f16)v.z; Ts[t + 3][c] = (f16)v.w;
            }
            __syncthreads();
            #pragma unroll
            for (int p = 0; p < 2; ++p) {
                const int t = (tid >> 3) + p * 32;
                const int ch = (tid & 7) * 8;
                *(f16x8*)(dst + (size_t)(t0 + t) * C_DIM + c0 + ch) =
                    *(const f16x8*)&Ts[t][ch];
            }
        }
    } else {
        const float* srcs[4] = {Wq, Wkv, Wkv + 262144, Wp};
        f16* dsts[4] = {Wqkh, Wqkh + 262144, Wvh, Wph};
        #pragma unroll
        for (int s = 0; s < 4; ++s) {
            const float* sp = srcs[s]; f16* dp = dsts[s];
            for (int i = blockIdx.x * 256 + tid; i < 65536; i += gridDim.x * 256) {
                const float4 v = *(const float4*)(sp + (size_t)i * 4);
                f16x4 h; h[0] = (f16)v.x; h[1] = (f16)v.y; h[2] = (f16)v.z; h[3] = (f16)v.w;
                *(f16x4*)(dp + (size_t)i * 4) = h;
            }
        }
    }
}

// ---------------------------------------------------------------------------
// Q/K projection, fp16 MFMA. m = tokens (global 8192), n = channels (1024).
// A = Xt[t][c], B = Wqkh[o][c]. C row=t, col=o. Q scaled by QSC.
// Outputs token-major Qh/Kh [bh][t][64].
// ---------------------------------------------------------------------------
__global__ __launch_bounds__(256) void qk_mfma(
    const f16* __restrict__ Xt, const f16* __restrict__ Wqkh,
    const float* __restrict__ bq, const float* __restrict__ bkv,
    f16* __restrict__ Qh, f16* __restrict__ Kh)
{
    __shared__ f16 As[128][40];
    __shared__ f16 Bs[128][40];
    const int tid = threadIdx.x;
    const int lane = tid & 63, w = tid >> 6;
    const int l15 = lane & 15, quad = lane >> 4;
    const int wy = w >> 1, wx = w & 1;
    const int mb0 = blockIdx.x * 128;   // token tile
    const int n0  = blockIdx.y * 128;   // channel tile

    f32x4 acc[4][4] = {};
    const int row = tid >> 2, c8 = (tid & 3) * 8;
    const f16* aptr = Xt + (size_t)mb0 * 512;
    const f16* bptr = Wqkh + (size_t)n0 * 512;

    uint4 ga0 = *(const uint4*)(aptr + (size_t)row * 512 + c8);
    uint4 ga1 = *(const uint4*)(aptr + (size_t)(row + 64) * 512 + c8);
    uint4 gb0 = *(const uint4*)(bptr + (size_t)row * 512 + c8);
    uint4 gb1 = *(const uint4*)(bptr + (size_t)(row + 64) * 512 + c8);

    for (int k0 = 0; k0 < 512; k0 += 32) {
        __syncthreads();
        *(uint4*)&As[row][c8] = ga0;
        *(uint4*)&As[row + 64][c8] = ga1;
        *(uint4*)&Bs[row][c8] = gb0;
        *(uint4*)&Bs[row + 64][c8] = gb1;
        if (k0 + 32 < 512) {
            ga0 = *(const uint4*)(aptr + (size_t)row * 512 + k0 + 32 + c8);
            ga1 = *(const uint4*)(aptr + (size_t)(row + 64) * 512 + k0 + 32 + c8);
            gb0 = *(const uint4*)(bptr + (size_t)row * 512 + k0 + 32 + c8);
            gb1 = *(const uint4*)(bptr + (size_t)(row + 64) * 512 + k0 + 32 + c8);
        }
        __syncthreads();
        f16x8 af[4], bf[4];
        #pragma unroll
        for (int i = 0; i < 4; ++i)
            af[i] = *(const f16x8*)&As[wy * 64 + i * 16 + l15][quad * 8];
        #pragma unroll
        for (int n = 0; n < 4; ++n)
            bf[n] = *(const f16x8*)&Bs[wx * 64 + n * 16 + l15][quad * 8];
        #pragma unroll
        for (int i = 0; i < 4; ++i)
            #pragma unroll
            for (int n = 0; n < 4; ++n)
                acc[i][n] = __builtin_amdgcn_mfma_f32_16x16x32_f16(af[i], bf[n], acc[i][n], 0, 0, 0);
    }

    #pragma unroll
    for (int nn = 0; nn < 4; ++nn) {
        const int o = n0 + wx * 64 + nn * 16 + l15;
        const bool isQ = (o < 512);
        const float bias = isQ ? bq[o] : bkv[o - 512];
        const int h = (o & 511) >> 6, d = o & 63;
        f16* base = isQ ? Qh : Kh;
        #pragma unroll
        for (int i = 0; i < 4; ++i) {
            const int tr = mb0 + wy * 64 + i * 16 + quad * 4;
            #pragma unroll
            for (int r = 0; r < 4; ++r) {
                const int tg = tr + r;
                const int bh = (tg >> 12) * NH + h;
                float v = acc[i][nn][r] + bias;
                if (isQ) v *= QSC;
                base[((size_t)bh * L_SEQ + (tg & 4095)) * DK + d] = (f16)v;
            }
        }
    }
}

// ---------------------------------------------------------------------------
// Channel-major projection, fp16 MFMA. m = channels (512), n = tokens (8192).
// A = Wh[o][c], B = Bsrc[t][c]. mode 0: V (f16 out, [bh*64+d][t]);
// mode 1: out-proj (fp32 out, [b][o][t]).
// ---------------------------------------------------------------------------
__global__ __launch_bounds__(256) void cproj_mfma(
    const f16* __restrict__ Bsrc, const f16* __restrict__ Wh,
    const float* __restrict__ bias, f16* __restrict__ outV,
    float* __restrict__ outP, int mode)
{
    __shared__ f16 As[128][40];
    __shared__ f16 Bs[128][40];
    const int tid = threadIdx.x;
    const int lane = tid & 63, w = tid >> 6;
    const int l15 = lane & 15, quad = lane >> 4;
    const int wy = w >> 1, wx = w & 1;
    const int n0  = blockIdx.x * 128;   // token tile
    const int mb0 = blockIdx.y * 128;   // channel tile

    f32x4 acc[4][4] = {};
    const int row = tid >> 2, c8 = (tid & 3) * 8;
    const f16* aptr = Wh + (size_t)mb0 * 512;
    const f16* bptr = Bsrc + (size_t)n0 * 512;

    uint4 ga0 = *(const uint4*)(aptr + (size_t)row * 512 + c8);
    uint4 ga1 = *(const uint4*)(aptr + (size_t)(row + 64) * 512 + c8);
    uint4 gb0 = *(const uint4*)(bptr + (size_t)row * 512 + c8);
    uint4 gb1 = *(const uint4*)(bptr + (size_t)(row + 64) * 512 + c8);

    for (int k0 = 0; k0 < 512; k0 += 32) {
        __syncthreads();
        *(uint4*)&As[row][c8] = ga0;
        *(uint4*)&As[row + 64][c8] = ga1;
        *(uint4*)&Bs[row][c8] = gb0;
        *(uint4*)&Bs[row + 64][c8] = gb1;
        if (k0 + 32 < 512) {
            ga0 = *(const uint4*)(aptr + (size_t)row * 512 + k0 + 32 + c8);
            ga1 = *(const uint4*)(aptr + (size_t)(row + 64) * 512 + k0 + 32 + c8);
            gb0 = *(const uint4*)(bptr + (size_t)row * 512 + k0 + 32 + c8);
            gb1 = *(const uint4*)(bptr + (size_t)(row + 64) * 512 + k0 + 32 + c8);
        }
        __syncthreads();
        f16x8 af[4], bf[4];
        #pragma unroll
        for (int i = 0; i < 4; ++i)
            af[i] = *(const f16x8*)&As[wy * 64 + i * 16 + l15][quad * 8];
        #pragma unroll
        for (int n = 0; n < 4; ++n)
            bf[n] = *(const f16x8*)&Bs[wx * 64 + n * 16 + l15][quad * 8];
        #pragma unroll
        for (int i = 0; i < 4; ++i)
            #pragma unroll
            for (int n = 0; n < 4; ++n)
                acc[i][n] = __builtin_amdgcn_mfma_f32_16x16x32_f16(af[i], bf[n], acc[i][n], 0, 0, 0);
    }

    #pragma unroll
    for (int i = 0; i < 4; ++i) {
        #pragma unroll
        for (int r = 0; r < 4; ++r) {
            const int o = mb0 + wy * 64 + i * 16 + quad * 4 + r;   // channel
            const float bv = bias[o];
            #pragma unroll
            for (int nn = 0; nn < 4; ++nn) {
                const int tg = n0 + wx * 64 + nn * 16 + l15;
                const float v = acc[i][nn][r] + bv;
                if (mode == 0) {
                    const int bh = (tg >> 12) * NH + (o >> 6);
                    outV[((size_t)bh * DK + (o & 63)) * L_SEQ + (tg & 4095)] = (f16)v;
                } else {
                    outP[((size_t)(tg >> 12) * C_DIM + o) * L_SEQ + (tg & 4095)] = v;
                }
            }
        }
    }
}

// ---------------------------------------------------------------------------
// Flash attention v8: split-s + block-level LDS staging of K/V (shared by all
// 4 waves — v7 had each wave redundantly load identical K/V fragments with
// 16-segment strided VMEM; that saturated the per-CU vector-memory path).
// Per block-iter VMEM: 16 contiguous 1KB loads. Pad-72 LDS rows: staging
// writes and fragment reads are bank-uniform. 2 barriers/iter, overlapped
// across 4 blocks/CU. No-max softmax; register prefetch of next tile.
// Partial O stored f16 [half*16+bh][d][t]; l f32 [half*16+bh][t].
// ---------------------------------------------------------------------------
__global__ __launch_bounds__(256) void flash16(
    const f16* __restrict__ Qh, const f16* __restrict__ Kh,
    const f16* __restrict__ Vh, f16* __restrict__ Opart,
    float* __restrict__ Lpart)
{
    __shared__ f16 KS[64][72];         // K tile [s][d]
    __shared__ f16 VS[64][72];         // V tile [d][s]
    __shared__ f16 PT[4][2][16][76];   // per-wave P^T [n][t][s]; pad 76
    const int tid = threadIdx.x;
    const int lane = tid & 63, w = tid >> 6;
    const int l15 = lane & 15, quad = lane >> 4;
    const int bh = blockIdx.x;          // XCD locality: bh % 8 picks the XCD
    const int t0 = blockIdx.y * 128;
    const int half = blockIdx.z;
    const int s_beg = half * 2048, s_end = half * 2048 + 2048;
    const int wtb = t0 + w * 32;
    const f16* Qg = Qh + (size_t)bh * L_SEQ * DK;
    const f16* Kg = Kh + (size_t)bh * L_SEQ * DK;
    const f16* Vg = Vh + (size_t)bh * DK * L_SEQ;

    // persistent Q B-fragments (already scaled by QSC in qk_mfma)
    f16x8 qf[2][2];
    #pragma unroll
    for (int n = 0; n < 2; ++n)
        #pragma unroll
        for (int ks = 0; ks < 2; ++ks)
            qf[n][ks] = *(const f16x8*)(Qg + (size_t)(wtb + n * 16 + l15) * DK + ks * 32 + quad * 8);

    f32x4 o_acc[4][2] = {};
    float rs[2] = {0.f, 0.f};
    h16x2 one2; one2[0] = (__fp16)1.f; one2[1] = (__fp16)1.f;

    // staging mapping: 256 thr, 16B/thr/pass, 2 passes cover a 64x64 f16 tile
    const int sr = tid >> 3;           // 0..31 (row within pass)
    const int sc = (tid & 7) * 8;      // f16 column chunk (contiguous 16B)

    uint4 gk[2], gv[2];
    #pragma unroll
    for (int p = 0; p < 2; ++p) {
        gk[p] = *(const uint4*)(Kg + (size_t)(s_beg + sr + p * 32) * DK + sc);
        gv[p] = *(const uint4*)(Vg + (size_t)(sr + p * 32) * L_SEQ + s_beg + sc);
    }
    #pragma unroll
    for (int p = 0; p < 2; ++p) {
        *(uint4*)&KS[sr + p * 32][sc] = gk[p];
        *(uint4*)&VS[sr + p * 32][sc] = gv[p];
    }
    __syncthreads();

    for (int s0 = s_beg; s0 < s_end; s0 += 64) {
        const bool more = (s0 + 64 < s_end);
        // prefetch next tile into registers (full iteration of slack)
        if (more) {
            #pragma unroll
            for (int p = 0; p < 2; ++p) {
                gk[p] = *(const uint4*)(Kg + (size_t)(s0 + 64 + sr + p * 32) * DK + sc);
                gv[p] = *(const uint4*)(Vg + (size_t)(sr + p * 32) * L_SEQ + s0 + 64 + sc);
            }
        }

        // S^T = K·Q^T : row = s, col = t   (K fragments from LDS)
        f32x4 S[4][2];
        #pragma unroll
        for (int m = 0; m < 4; ++m) {
            const f16x8 k0 = *(const f16x8*)&KS[m * 16 + l15][quad * 8];
            const f16x8 k1 = *(const f16x8*)&KS[m * 16 + l15][32 + quad * 8];
            #pragma unroll
            for (int n = 0; n < 2; ++n) {
                f32x4 z = {0.f, 0.f, 0.f, 0.f};
                z = __builtin_amdgcn_mfma_f32_16x16x32_f16(k0, qf[n][0], z, 0, 0, 0);
                S[m][n] = __builtin_amdgcn_mfma_f32_16x16x32_f16(k1, qf[n][1], z, 0, 0, 0);
            }
        }

        // P = exp2(S') via raw v_exp_f32; pack RTZ; l += dot2(P_rounded, 1)
        #pragma unroll
        for (int n = 0; n < 2; ++n) {
            #pragma unroll
            for (int m = 0; m < 4; ++m) {
                const h16x2 q01 = __builtin_amdgcn_cvt_pkrtz(
                    __builtin_amdgcn_exp2f(S[m][n][0]),
                    __builtin_amdgcn_exp2f(S[m][n][1]));
                const h16x2 q23 = __builtin_amdgcn_cvt_pkrtz(
                    __builtin_amdgcn_exp2f(S[m][n][2]),
                    __builtin_amdgcn_exp2f(S[m][n][3]));
                rs[n] = __builtin_amdgcn_fdot2(q01, one2, rs[n], false);
                rs[n] = __builtin_amdgcn_fdot2(q23, one2, rs[n], false);
                union { h16x2 h2[2]; uint2 u2; } pr;
                pr.h2[0] = q01; pr.h2[1] = q23;
                *(uint2*)&PT[w][n][l15][m * 16 + quad * 4] = pr.u2;
            }
        }

        // O += P·V  (A = V-frag from LDS [d][s], B = P-frag from LDS)
        #pragma unroll
        for (int ks = 0; ks < 2; ++ks) {
            f16x8 pf[2];
            #pragma unroll
            for (int n = 0; n < 2; ++n)
                pf[n] = *(const f16x8*)&PT[w][n][l15][ks * 32 + quad * 8];
            #pragma unroll
            for (int m = 0; m < 4; ++m) {
                const f16x8 vfm = *(const f16x8*)&VS[m * 16 + l15][ks * 32 + quad * 8];
                #pragma unroll
                for (int n = 0; n < 2; ++n)
                    o_acc[m][n] = __builtin_amdgcn_mfma_f32_16x16x32_f16(vfm, pf[n], o_acc[m][n], 0, 0, 0);
            }
        }

        __syncthreads();                 // all waves done reading KS/VS
        if (more) {
            #pragma unroll
            for (int p = 0; p < 2; ++p) {
                *(uint4*)&KS[sr + p * 32][sc] = gk[p];
                *(uint4*)&VS[sr + p * 32][sc] = gv[p];
            }
        }
        __syncthreads();                 // next tile ready
    }

    // l partial: reduce over quads, store from quad 0
    float r0 = rs[0], r1 = rs[1];
    r0 += __shfl_xor(r0, 16, 64); r0 += __shfl_xor(r0, 32, 64);
    r1 += __shfl_xor(r1, 16, 64); r1 += __shfl_xor(r1, 32, 64);
    if (quad == 0) {
        float* Lp = Lpart + (size_t)(half * 16 + bh) * L_SEQ + wtb;
        Lp[l15] = r0;
        Lp[16 + l15] = r1;
    }

    // O partial: C layout row = d = m*16+quad*4+r, col = t = wtb + n*16+l15
    f16* Op = Opart + (size_t)(half * 16 + bh) * DK * L_SEQ;
    #pragma unroll
    for (int m = 0; m < 4; ++m)
        #pragma unroll
        for (int n = 0; n < 2; ++n)
            #pragma unroll
            for (int r = 0; r < 4; ++r)
                Op[(size_t)(m * 16 + quad * 4 + r) * L_SEQ + wtb + n * 16 + l15] =
                    (f16)o_acc[m][n][r];
}

// ---------------------------------------------------------------------------
// combine: O = (Olo + Ohi) / (llo + lhi), transpose [d][t] -> token-major
// f16 [b*4096+t][512] for the out-proj B operand. One block per (bh, 64-t).
// ---------------------------------------------------------------------------
__global__ __launch_bounds__(256) void combine(
    const f16* __restrict__ Opart, const float* __restrict__ Lpart,
    f16* __restrict__ Oh)
{
    __shared__ f16 Ts[64][72];
    __shared__ float Linv[64];
    const int tid = threadIdx.x;
    const int bh = blockIdx.y, b = bh >> 3, h = bh & 7;
    const int t0 = blockIdx.x * 64;
    if (tid < 64) {
        const float lo = Lpart[(size_t)bh * L_SEQ + t0 + tid];
        const float hi = Lpart[(size_t)(16 + bh) * L_SEQ + t0 + tid];
        Linv[tid] = 1.f / (lo + hi);
    }
    __syncthreads();
    const f16* Plo = Opart + (size_t)bh * DK * L_SEQ;
    const f16* Phi = Opart + (size_t)(16 + bh) * DK * L_SEQ;
    const int d = tid >> 4;
    const int tt = (tid & 15) * 4;
    #pragma unroll
    for (int p = 0; p < 4; ++p) {
        const int dd = d + p * 16;
        const size_t off = (size_t)dd * L_SEQ + t0 + tt;
        const f16x4 lo = *(const f16x4*)(Plo + off);
        const f16x4 hi = *(const f16x4*)(Phi + off);
        #pragma unroll
        for (int j = 0; j < 4; ++j)
            Ts[tt + j][dd] = (f16)(((float)lo[j] + (float)hi[j]) * Linv[tt + j]);
    }
    __syncthreads();
    const int tr = tid >> 2, ch = (tid & 3) * 16;
    f16* dst = Oh + ((size_t)(b * L_SEQ + t0 + tr)) * C_DIM + h * DK + ch;
    *(f16x8*)dst = *(const f16x8*)&Ts[tr][ch];
    *(f16x8*)(dst + 8) = *(const f16x8*)&Ts[tr][ch + 8];
}

// ---------------------------------------------------------------------------
extern "C" void kernel_launch(void* const* d_in, const int* in_sizes, int n_in,
                              void* d_out, int out_size, void* d_ws, size_t ws_size,
                              hipStream_t stream) {
    (void)in_sizes; (void)n_in; (void)out_size; (void)ws_size;
    const float* x   = (const float*)d_in[0];
    const float* Wq  = (const float*)d_in[1];
    const float* bq  = (const float*)d_in[2];
    const float* Wkv = (const float*)d_in[3];
    const float* bkv = (const float*)d_in[4];
    const float* Wp  = (const float*)d_in[5];
    const float* bp  = (const float*)d_in[6];
    float* out = (float*)d_out;

    f16* Xt    = (f16*)d_ws;           // [8192][512]
    f16* Wqkh  = Xt + 4194304;         // [1024][512]
    f16* Wvh   = Wqkh + 524288;        // [512][512]
    f16* Wph   = Wvh + 262144;         // [512][512]
    f16* Qh    = Wph + 262144;         // [16][4096][64]
    f16* Kh    = Qh + 4194304;
    f16* Vh    = Kh + 4194304;         // [16*64][4096]
    f16* Oh    = Vh + 4194304;         // [8192][512]
    f16* Opart = Oh + 4194304;         // [2*16][64][4096] f16
    float* Lpart = (float*)(Opart + 8388608);  // [2*16][4096] f32

    prep<<<dim3(128, 1, 3), 256, 0, stream>>>(x, Wq, Wkv, Wp, Xt, Wqkh, Wvh, Wph);
    qk_mfma<<<dim3(64, 8), 256, 0, stream>>>(Xt, Wqkh, bq, bkv, Qh, Kh);
    cproj_mfma<<<dim3(64, 4), 256, 0, stream>>>(Xt, Wvh, bkv + 512, Vh, nullptr, 0);
    flash16<<<dim3(16, 32, 2), 256, 0, stream>>>(Qh, Kh, Vh, Opart, Lpart);
    combine<<<dim3(64, 16), 256, 0, stream>>>(Opart, Lpart, Oh);
    cproj_mfma<<<dim3(64, 4), 256, 0, stream>>>(Oh, Wph, bp, nullptr, out, 1);
}